// Round 1
// baseline (3469.013 us; speedup 1.0000x reference)
//
#include <hip/hip_runtime.h>
#include <hip/hip_bf16.h>
#include <stdint.h>
#include <math.h>

typedef unsigned long long ull;

// ================= Conv3x3 (SAME) + bias + BN + LeakyReLU =================
// Block: 256 thr. Tile: 64 couts x 16 rows x 8 cols. Thread: 4 couts x 1 row x 8 cols.
template<int CIN, int COUT, int H, int W>
__global__ __launch_bounds__(256)
void conv3x3_bn_lrelu(const float* __restrict__ x, const float* __restrict__ wgt,
                      const float* __restrict__ bias, const float* __restrict__ gamma,
                      const float* __restrict__ beta, const float* __restrict__ mean,
                      const float* __restrict__ var, float* __restrict__ y) {
  constexpr int RT = 16, TC = 64, CCH = 8;
  const int nRT = (H + RT - 1) / RT;
  const int bx = blockIdx.x;            // col tile (8 wide)
  const int rt = blockIdx.y % nRT;      // row tile
  const int ct = blockIdx.y / nRT;      // cout tile
  const int b  = blockIdx.z;
  const int tid = threadIdx.x;
  const int cg = tid >> 4;              // 0..15 -> 4 couts each
  const int r  = tid & 15;              // local output row

  const int gr0 = rt * RT, gc0 = bx * 8;

  __shared__ float ilds[CCH][RT + 2][12];   // 10 cols used, stride 12 (48B, f4-aligned)
  __shared__ float wlds[CCH][9][TC];

  float acc[4][8];
#pragma unroll
  for (int c = 0; c < 4; ++c)
#pragma unroll
    for (int j = 0; j < 8; ++j) acc[c][j] = 0.f;

  const float* xb = x + (size_t)b * CIN * H * W;

  for (int ic0 = 0; ic0 < CIN; ic0 += CCH) {
    __syncthreads();
    // stage input patch: CCH x 18 x 10 (with SAME-pad zeros)
    for (int idx = tid; idx < CCH * (RT + 2) * 10; idx += 256) {
      int ic = idx / ((RT + 2) * 10);
      int rem = idx % ((RT + 2) * 10);
      int rr = rem / 10, cc = rem % 10;
      int gr = gr0 - 1 + rr, gc = gc0 - 1 + cc;
      float v = 0.f;
      if (gr >= 0 && gr < H && gc >= 0 && gc < W)
        v = xb[((size_t)(ic0 + ic) * H + gr) * W + gc];
      ilds[ic][rr][cc] = v;
    }
    // stage weights: [ic][k][cout] ; global w[(ct*64+cc)][ic0+ic][kh][kw]
    for (int idx = tid; idx < TC * CCH * 9; idx += 256) {
      int cc = idx / (CCH * 9);
      int t = idx % (CCH * 9);
      int ic = t / 9, k = t % 9;
      wlds[ic][k][cc] = wgt[((size_t)(ct * TC + cc) * CIN + ic0 + ic) * 9 + k];
    }
    __syncthreads();
#pragma unroll 1
    for (int ic = 0; ic < CCH; ++ic) {
#pragma unroll
      for (int kh = 0; kh < 3; ++kh) {
        const float4* rowp = (const float4*)&ilds[ic][r + kh][0];
        float4 a0 = rowp[0], a1 = rowp[1], a2 = rowp[2];
        float in_[12] = {a0.x, a0.y, a0.z, a0.w, a1.x, a1.y, a1.z, a1.w,
                         a2.x, a2.y, a2.z, a2.w};
#pragma unroll
        for (int kw = 0; kw < 3; ++kw) {
          float4 wv = *(const float4*)&wlds[ic][kh * 3 + kw][cg * 4];
#pragma unroll
          for (int j = 0; j < 8; ++j) {
            acc[0][j] = fmaf(wv.x, in_[j + kw], acc[0][j]);
            acc[1][j] = fmaf(wv.y, in_[j + kw], acc[1][j]);
            acc[2][j] = fmaf(wv.z, in_[j + kw], acc[2][j]);
            acc[3][j] = fmaf(wv.w, in_[j + kw], acc[3][j]);
          }
        }
      }
    }
  }
  // epilogue: +bias, BN, leaky relu, store NCHW
  const int row = gr0 + r;
  if (row < H) {
#pragma unroll
    for (int c = 0; c < 4; ++c) {
      int oc = ct * TC + cg * 4 + c;
      float scl = gamma[oc] / sqrtf(var[oc] + 1e-5f);
      float bs = bias[oc], mn = mean[oc], bt = beta[oc];
#pragma unroll
      for (int j = 0; j < 8; ++j) {
        int col = gc0 + j;
        if (col < W) {
          float v = (acc[c][j] + bs - mn) * scl + bt;
          v = v > 0.f ? v : 0.1f * v;
          y[((size_t)(b * COUT + oc) * H + row) * W + col] = v;
        }
      }
    }
  }
}

// ================= fused 1x1 conv (255 couts) + decode =================
// Block: 256 thr. Tile: 64 px x 256 oc (255 real). Thread: 4 px x 16 oc.
// After GEMM: full 255-ch tile in LDS (xor-swizzled), then per-anchor decode.
template<int CIN>
__global__ __launch_bounds__(256)
void head1x1_decode(const float* __restrict__ act, const float* __restrict__ pw,
                    const float* __restrict__ pb,
                    int HW, int Wl, float strd, int P0,
                    float aw0, float ah0, float aw1, float ah1, float aw2, float ah2,
                    float* __restrict__ out, float* __restrict__ boxes,
                    float* __restrict__ scb, int* __restrict__ clsb) {
  __shared__ union {
    struct { float a[8][64]; float w[8][256]; } s;
    float pred[64 * 256];                      // 64KB
  } u;
  const int pt = blockIdx.x, b = blockIdx.y;
  const int p0 = pt * 64;
  const int tid = threadIdx.x;
  const int og = tid & 15;   // 16 ocs: og*16..
  const int pg = tid >> 4;   // 4 px:  pg*4..

  float acc[4][16];
#pragma unroll
  for (int pi = 0; pi < 4; ++pi)
#pragma unroll
    for (int k = 0; k < 16; ++k) acc[pi][k] = 0.f;

  for (int ic0 = 0; ic0 < CIN; ic0 += 8) {
    __syncthreads();
    for (int idx = tid; idx < 512; idx += 256) {
      int ic = idx >> 6, px = idx & 63;
      int p = p0 + px;
      u.s.a[ic][px] = (p < HW) ? act[(size_t)(b * CIN + ic0 + ic) * HW + p] : 0.f;
    }
    for (int idx = tid; idx < 2048; idx += 256) {
      int oc = idx >> 3, ic = idx & 7;
      u.s.w[ic][oc] = (oc < 255) ? pw[(size_t)oc * CIN + ic0 + ic] : 0.f;
    }
    __syncthreads();
#pragma unroll 1
    for (int ic = 0; ic < 8; ++ic) {
      float4 a4 = *(const float4*)&u.s.a[ic][pg * 4];
      const float4* wrow = (const float4*)&u.s.w[ic][og * 16];
      float4 w0 = wrow[0], w1 = wrow[1], w2 = wrow[2], w3 = wrow[3];
      float av[4] = {a4.x, a4.y, a4.z, a4.w};
      float wv[16] = {w0.x, w0.y, w0.z, w0.w, w1.x, w1.y, w1.z, w1.w,
                      w2.x, w2.y, w2.z, w2.w, w3.x, w3.y, w3.z, w3.w};
#pragma unroll
      for (int pi = 0; pi < 4; ++pi)
#pragma unroll
        for (int k = 0; k < 16; ++k)
          acc[pi][k] = fmaf(av[pi], wv[k], acc[pi][k]);
    }
  }
  __syncthreads();
  // +pb, write swizzled pred tile to LDS
  float pbv[16];
#pragma unroll
  for (int k = 0; k < 16; ++k) {
    int oc = og * 16 + k;
    pbv[k] = (oc < 255) ? pb[oc] : 0.f;
  }
#pragma unroll
  for (int pi = 0; pi < 4; ++pi) {
    int px = pg * 4 + pi;
    int swz = px & 28;
#pragma unroll
    for (int k4 = 0; k4 < 4; ++k4) {
      float4 v;
      v.x = acc[pi][k4 * 4 + 0] + pbv[k4 * 4 + 0];
      v.y = acc[pi][k4 * 4 + 1] + pbv[k4 * 4 + 1];
      v.z = acc[pi][k4 * 4 + 2] + pbv[k4 * 4 + 2];
      v.w = acc[pi][k4 * 4 + 3] + pbv[k4 * 4 + 3];
      *(float4*)&u.pred[px * 256 + (((og * 16 + k4 * 4) ^ swz))] = v;
    }
  }
  __syncthreads();
  // decode: 192 threads = 64 px x 3 anchors
  if (tid < 192) {
    const int px = tid & 63, a = tid >> 6;
    const int p = p0 + px;
    if (p < HW) {
      const int swz = px & 28;
      const float* pr = &u.pred[px * 256];
#define RD(ch) pr[(ch) ^ swz]
      float conf = RD(a);
      int ch0 = 3 + 80 * a;
      float m = -1e30f; int ci = 0;
      for (int i = 0; i < 80; ++i) {
        float v = RD(ch0 + i);
        if (v > m) { m = v; ci = i; }
      }
      float ssum = 0.f;
      for (int i = 0; i < 80; ++i) ssum += expf(RD(ch0 + i) - m);
      float sig = 1.f / (1.f + expf(-conf));
      float sc = sig / ssum;
      float tx = RD(243 + 4 * a), ty = RD(244 + 4 * a);
      float tw = RD(245 + 4 * a), th = RD(246 + 4 * a);
#undef RD
      float gx = (float)(p % Wl), gy = (float)(p / Wl);
      float aw = (a == 0) ? aw0 : ((a == 1) ? aw1 : aw2);
      float ah = (a == 0) ? ah0 : ((a == 1) ? ah1 : ah2);
      float cx = (1.f / (1.f + expf(-tx)) + gx) * strd;
      float cy = (1.f / (1.f + expf(-ty)) + gy) * strd;
      float bw = expf(tw) * aw, bh = expf(th) * ah;
      float x1 = fminf(fmaxf((cx - bw * 0.5f) / 640.f, 0.f), 1.f);
      float y1 = fminf(fmaxf((cy - bh * 0.5f) / 640.f, 0.f), 1.f);
      float x2 = fminf(fmaxf((cx + bw * 0.5f) / 640.f, 0.f), 1.f);
      float y2 = fminf(fmaxf((cy + bh * 0.5f) / 640.f, 0.f), 1.f);
      int n = (P0 + p) * 3 + a;
      size_t g = (size_t)b * 25200 + n;
      out[g * 5 + 0] = (x1 + x2) * 0.5f * 640.f;
      out[g * 5 + 1] = (y1 + y2) * 0.5f * 640.f;
      out[g * 5 + 2] = (x2 - x1) * 640.f;
      out[g * 5 + 3] = (y2 - y1) * 640.f;
      out[g * 5 + 4] = sc;
      out[(size_t)8 * 25200 * 5 + g] = (float)ci;   // cls_inds
      out[(size_t)8 * 25200 * 6 + g] = 0.f;          // keep init
      boxes[g * 4 + 0] = x1; boxes[g * 4 + 1] = y1;
      boxes[g * 4 + 2] = x2; boxes[g * 4 + 3] = y2;
      scb[g] = sc; clsb[g] = ci;
    }
  }
}

// ================= top-k (compact + bitonic) =================
__global__ __launch_bounds__(256)
void topk_sort(const float* __restrict__ scb, const float* __restrict__ boxes,
               const int* __restrict__ clsb,
               int* __restrict__ tidx, int* __restrict__ tval, float* __restrict__ tbox) {
  __shared__ ull keys[4096];
  __shared__ int cnt;
  const int b = blockIdx.x, tid = threadIdx.x;
  if (tid == 0) cnt = 0;
  __syncthreads();
  for (int n = tid; n < 25200; n += 256) {
    float s = scb[(size_t)b * 25200 + n];
    if (s >= 0.3f) {
      int p = atomicAdd(&cnt, 1);
      if (p < 4096)
        keys[p] = ((ull)__float_as_uint(s) << 32) | (ull)(0xFFFFFFFFu - (unsigned)n);
    }
  }
  __syncthreads();
  int c = min(cnt, 4096);
  int P2 = 1024;
  while (P2 < c) P2 <<= 1;
  for (int i = c + tid; i < P2; i += 256) keys[i] = 0ull;
  __syncthreads();
  for (int len = 2; len <= P2; len <<= 1) {
    for (int j = len >> 1; j > 0; j >>= 1) {
      for (int x = tid; x < P2; x += 256) {
        int y = x ^ j;
        if (y > x) {
          ull a = keys[x], bb = keys[y];
          bool up = (x & len) == 0;   // descending overall
          if (up ? (a < bb) : (a > bb)) { keys[x] = bb; keys[y] = a; }
        }
      }
      __syncthreads();
    }
  }
  for (int i = tid; i < 1000; i += 256) {
    ull k = keys[i];
    int valid = (k != 0ull) ? 1 : 0;
    int n = valid ? (int)(0xFFFFFFFFu - (unsigned)(k & 0xFFFFFFFFull)) : 0;
    float cls = (float)clsb[(size_t)b * 25200 + n];
    float off = cls * 4.0f;
    const float* bp = &boxes[((size_t)b * 25200 + n) * 4];
    tidx[b * 1000 + i] = n;
    tval[b * 1000 + i] = valid;
    tbox[(b * 1000 + i) * 4 + 0] = bp[0] + off;
    tbox[(b * 1000 + i) * 4 + 1] = bp[1] + off;
    tbox[(b * 1000 + i) * 4 + 2] = bp[2] + off;
    tbox[(b * 1000 + i) * 4 + 3] = bp[3] + off;
  }
}

// ================= pairwise suppression bitmasks =================
__global__ __launch_bounds__(1024)
void supmask(const float* __restrict__ tbox, ull* __restrict__ sup) {
  __shared__ float4 bx[1000];
  __shared__ float ar[1000];
  const int b = blockIdx.x, tid = threadIdx.x;
  for (int i = tid; i < 1000; i += 1024) {
    float4 v = *(const float4*)&tbox[((size_t)b * 1000 + i) * 4];
    bx[i] = v;
    ar[i] = (v.z - v.x) * (v.w - v.y);
  }
  __syncthreads();
  if (tid < 1000) {
    float4 bi = bx[tid];
    float ai = ar[tid];
    ull w = 0;
    for (int j = 0; j < 1000; ++j) {
      float4 bj = bx[j];
      float xx1 = fmaxf(bi.x, bj.x), yy1 = fmaxf(bi.y, bj.y);
      float xx2 = fminf(bi.z, bj.z), yy2 = fminf(bi.w, bj.w);
      float inter = fmaxf(1e-28f, xx2 - xx1) * fmaxf(1e-28f, yy2 - yy1);
      float iou = inter / (ai + ar[j] - inter);
      if (iou > 0.5f) w |= 1ull << (j & 63);
      if ((j & 63) == 63) { sup[((size_t)b * 1000 + tid) * 16 + (j >> 6)] = w; w = 0; }
    }
    sup[((size_t)b * 1000 + tid) * 16 + 15] = w;
  }
}

// ================= greedy NMS (serial, ballot-driven) =================
__global__ __launch_bounds__(64)
void nms_kernel(const ull* __restrict__ sup, const int* __restrict__ tval,
                const int* __restrict__ tidx, float* __restrict__ keep_out) {
  const int b = blockIdx.x, lane = threadIdx.x;   // 64 threads, 1 wave
  __shared__ ull slds[64][17];
  ull keepw = 0;   // lane l (l<16) holds keep word l (bits only for decided j<i)
  for (int ch = 0; ch < 16; ++ch) {
    int i0 = ch * 64;
    int nIn = min(64, 1000 - i0);
    for (int k = 0; k < 16; ++k) {
      int linear = k * 64 + lane;
      int row = linear >> 4, w = linear & 15;
      slds[row][w] = (row < nIn) ? sup[((size_t)b * 1000 + i0 + row) * 16 + w] : 0ull;
    }
    int myvalid = (lane < nIn) ? tval[b * 1000 + i0 + lane] : 0;
    int myidx = (lane < nIn) ? tidx[b * 1000 + i0 + lane] : 0;
    __syncthreads();
    for (int li = 0; li < nIn; ++li) {
      ull m = (lane < 16) ? (keepw & slds[li][lane]) : 0ull;
      bool sup_any = __any(m != 0ull);
      int v = __shfl(myvalid, li);
      bool keep_i = v && !sup_any;
      if (keep_i) {
        if (lane == ch) keepw |= 1ull << li;
        if (lane == li) keep_out[(size_t)b * 25200 + myidx] = 1.0f;
      }
    }
    __syncthreads();
  }
}

// ================= launch =================
extern "C" void kernel_launch(void* const* d_in, const int* in_sizes, int n_in,
                              void* d_out, int out_size, void* d_ws, size_t ws_size,
                              hipStream_t stream) {
  const float* p3 = (const float*)d_in[0];
  const float* p4 = (const float*)d_in[1];
  const float* p5 = (const float*)d_in[2];
  auto L = [&](int lvl, int k) { return (const float*)d_in[3 + lvl * 8 + k]; };
  float* out = (float*)d_out;
  char* ws = (char*)d_ws;
  float* act = (float*)ws;                 size_t o = (size_t)13107200 * 4;
  float* boxes = (float*)(ws + o);         o += (size_t)806400 * 4;
  float* scb = (float*)(ws + o);           o += (size_t)201600 * 4;
  int* clsb = (int*)(ws + o);              o += (size_t)201600 * 4;
  int* tidx = (int*)(ws + o);              o += 8000 * 4;
  int* tval = (int*)(ws + o);              o += 8000 * 4;
  float* tbox = (float*)(ws + o);          o += 32000 * 4;
  ull* sup = (ull*)(ws + o);               o += (size_t)128000 * 8;

  // ---- level 1: 128->256, 80x80, stride 8
  conv3x3_bn_lrelu<128, 256, 80, 80><<<dim3(10, 5 * 4, 8), 256, 0, stream>>>(
      p3, L(0, 0), L(0, 1), L(0, 2), L(0, 3), L(0, 4), L(0, 5), act);
  head1x1_decode<256><<<dim3(100, 8), 256, 0, stream>>>(
      act, L(0, 6), L(0, 7), 6400, 80, 8.f, 0,
      32.64f, 47.68f, 50.24f, 108.16f, 126.72f, 96.32f, out, boxes, scb, clsb);
  // ---- level 2: 256->512, 40x40, stride 16
  conv3x3_bn_lrelu<256, 512, 40, 40><<<dim3(5, 3 * 8, 8), 256, 0, stream>>>(
      p4, L(1, 0), L(1, 1), L(1, 2), L(1, 3), L(1, 4), L(1, 5), act);
  head1x1_decode<512><<<dim3(25, 8), 256, 0, stream>>>(
      act, L(1, 6), L(1, 7), 1600, 40, 16.f, 6400,
      78.4f, 201.92f, 178.24f, 178.56f, 129.6f, 294.72f, out, boxes, scb, clsb);
  // ---- level 3: 512->1024, 20x20, stride 32
  conv3x3_bn_lrelu<512, 1024, 20, 20><<<dim3(3, 2 * 16, 8), 256, 0, stream>>>(
      p5, L(2, 0), L(2, 1), L(2, 2), L(2, 3), L(2, 4), L(2, 5), act);
  head1x1_decode<1024><<<dim3(7, 8), 256, 0, stream>>>(
      act, L(2, 6), L(2, 7), 400, 20, 32.f, 8000,
      331.84f, 194.56f, 227.84f, 325.76f, 365.44f, 358.72f, out, boxes, scb, clsb);
  // ---- NMS pipeline
  topk_sort<<<8, 256, 0, stream>>>(scb, boxes, clsb, tidx, tval, tbox);
  supmask<<<8, 1024, 0, stream>>>(tbox, sup);
  nms_kernel<<<8, 64, 0, stream>>>(sup, tval, tidx, out + (size_t)8 * 25200 * 6);
}